// Round 12
// baseline (2017.704 us; speedup 1.0000x reference)
//
#include <hip/hip_runtime.h>
#include <math.h>

#define N 1024
#define C 384
#define H 12
#define DP 128
#define HP 144
#define QBL 8      // q-rows per block
#define MSL 128    // keys per m-slice (per block)
#define NSLICE 8
#define SCALING 0.17677669529663687f
#define LN_EPS 1e-5f

// ---------------- K1: fused projections GEMM (r8, unchanged) ----------------
__global__ __launch_bounds__(256) void k_qkv(
    const float* __restrict__ single,
    const float* __restrict__ Wq, const float* __restrict__ bq,
    const float* __restrict__ Wk, const float* __restrict__ bk,
    const float* __restrict__ Wv, const float* __restrict__ bv,
    const float* __restrict__ Wpq, const float* __restrict__ bpq,
    const float* __restrict__ Wpk, const float* __restrict__ bpk,
    float* __restrict__ q, float* __restrict__ kcg, float* __restrict__ v,
    float* __restrict__ qp, float* __restrict__ kp)
{
  __shared__ __align__(16) float A_s[64 * 33];
  __shared__ __align__(16) float B_s[32 * 48];
  int t = threadIdx.x;
  int nt = blockIdx.x, mt = blockIdx.y;
  int m0 = mt * 64;
  const float* W; const float* bias; int ld, kind, cb;
  if (nt < 8)       { W = Wq;  bias = bq;  ld = C;  cb = nt * 48;        kind = 0; }
  else if (nt < 16) { W = Wk;  bias = bk;  ld = C;  cb = (nt - 8) * 48;  kind = 1; }
  else if (nt < 24) { W = Wv;  bias = bv;  ld = C;  cb = (nt - 16) * 48; kind = 2; }
  else if (nt < 27) { W = Wpq; bias = bpq; ld = HP; cb = (nt - 24) * 48; kind = 3; }
  else              { W = Wpk; bias = bpk; ld = HP; cb = (nt - 27) * 48; kind = 4; }
  int tr = t >> 4, tc = t & 15;
  float acc[4][3] = {};
  for (int k0 = 0; k0 < C; k0 += 32) {
    if (k0) __syncthreads();
    #pragma unroll
    for (int i = 0; i < 8; i++) {
      int fi = i * 256 + t; int row = fi >> 5, col = fi & 31;
      A_s[row * 33 + col] = single[(m0 + row) * C + k0 + col];
    }
    #pragma unroll
    for (int i = 0; i < 6; i++) {
      int fi = i * 256 + t; int row = fi / 48, col = fi % 48;
      B_s[row * 48 + col] = W[(k0 + row) * ld + cb + col];
    }
    __syncthreads();
    #pragma unroll
    for (int k = 0; k < 32; k++) {
      float a[4], b[3];
      #pragma unroll
      for (int r = 0; r < 4; r++) a[r] = A_s[(tr * 4 + r) * 33 + k];
      #pragma unroll
      for (int c = 0; c < 3; c++) b[c] = B_s[k * 48 + tc * 3 + c];
      #pragma unroll
      for (int r = 0; r < 4; r++)
        #pragma unroll
        for (int c = 0; c < 3; c++) acc[r][c] = fmaf(a[r], b[c], acc[r][c]);
    }
  }
  #pragma unroll
  for (int c = 0; c < 3; c++) {
    int col = cb + tc * 3 + c;
    float bb = bias[col];
    #pragma unroll
    for (int r = 0; r < 4; r++) {
      int row = m0 + tr * 4 + r;
      float val = acc[r][c] + bb;
      if (kind == 0)      q[row * C + col] = val;
      else if (kind == 1) kcg[((col >> 5) * N + row) * 48 + (col & 31)] = val;
      else if (kind == 2) v[row * C + col] = val;
      else if (kind == 3) qp[row * HP + col] = val;
      else                kp[row * HP + col] = val;
    }
  }
}

// ---------------- K1b: rotate points, sq/sk sums (r8, unchanged) ----------------
__global__ __launch_bounds__(256) void k_rot(
    const float* __restrict__ qp, const float* __restrict__ kp,
    const float* __restrict__ rot,
    float* __restrict__ qg, float* __restrict__ kcg,
    float* __restrict__ sq, float* __restrict__ sknh)
{
  __shared__ __align__(16) float qp_s[HP], kp_s[HP], rot_s[9], q2_s[HP], k2_s[HP];
  int n = blockIdx.x, t = threadIdx.x;
  if (t < HP) { qp_s[t] = qp[n * HP + t]; kp_s[t] = kp[n * HP + t]; }
  if (t < 9)  rot_s[t] = rot[n * 9 + t];
  __syncthreads();
  if (t < HP) {
    int h = t / 12, r12 = t % 12, y = r12 >> 2, p = r12 & 3;
    float qgv = rot_s[y*3] * qp_s[h*12 + p] + rot_s[y*3+1] * qp_s[h*12 + 4 + p]
              + rot_s[y*3+2] * qp_s[h*12 + 8 + p];
    float kgv = rot_s[y*3] * kp_s[h*12 + p] + rot_s[y*3+1] * kp_s[h*12 + 4 + p]
              + rot_s[y*3+2] * kp_s[h*12 + 8 + p];
    qg[n * HP + t] = qgv;
    kcg[(h * N + n) * 48 + 32 + r12] = kgv;
    q2_s[t] = qgv * qgv; k2_s[t] = kgv * kgv;
  }
  if (t < 48) kcg[((t >> 2) * N + n) * 48 + 44 + (t & 3)] = 0.f;  // zero pad
  __syncthreads();
  if (t < H) {
    float s1 = 0.f, s2 = 0.f;
    #pragma unroll
    for (int e = 0; e < 12; e++) { s1 += q2_s[t * 12 + e]; s2 += k2_s[t * 12 + e]; }
    sq[n * H + t] = s1; sknh[n * H + t] = s2;
  }
}

// ---------------- K1c: LDS-tiled transpose kcg -> kcT (coalesced both sides) ----------------
__global__ __launch_bounds__(256) void k_tr(
    const float* __restrict__ kcg, float* __restrict__ kcT)
{
  __shared__ __align__(16) float4 ks[64][13];  // pad 13
  int bid = blockIdx.x;
  int h = bid >> 4, n0 = (bid & 15) * 64;
  int t = threadIdx.x;
  #pragma unroll
  for (int i = 0; i < 3; i++) {
    int f = i * 256 + t; int row = f / 12, c4 = f % 12;
    ks[row][c4] = *(const float4*)&kcg[((long)h * N + n0 + row) * 48 + c4 * 4];
  }
  __syncthreads();
  float4* kcT4 = (float4*)kcT;
  #pragma unroll
  for (int i = 0; i < 3; i++) {
    int f = i * 256 + t; int c4 = f >> 6, row = f & 63;
    kcT4[(long)(h * 12 + c4) * N + n0 + row] = ks[row][c4];
  }
}

// ---------------- K2: FUSED pair-bias + attention, blocked ----------------
// Block = (8 q-rows, 128-key m-slice, all 12 heads). Grid 1024 = 128 qb x 8 msl,
// XCD-swizzled so each XCD owns one m-slice (kc/v slice L2-resident).
// Per 64-m sub-tile: PB phase (k_pb quad-dot, pair read once globally) ->
// pbx LDS; then per head: QK (lane=m, kcT coalesced, qc broadcast, max-free
// exp) -> wave-private p_s -> AV (r8 lanes=(c,seg), natural v). Partial
// o/lsum written to opart/lpart (additive across slices thanks to max-free).
__global__ __launch_bounds__(256, 2) void k_fused(
    const float4* __restrict__ pair4, const float* __restrict__ Wp,
    const float* __restrict__ bp, const float* __restrict__ sq,
    const float* __restrict__ sknh, const float* __restrict__ q,
    const float* __restrict__ qg, const float* __restrict__ kcT,
    const float* __restrict__ v, float* __restrict__ opart,
    float* __restrict__ lpart)
{
  __shared__ __align__(16) float wp_s[12 * 128];     // [h][d]      6 KB
  __shared__ __align__(16) float qc_s[QBL][12][48];  // prescaled  18 KB
  __shared__ __align__(16) float pbx[QBL][12][64];   // bias tile  24 KB
  __shared__ __align__(16) float p_s[4][QBL][64];    // wave-priv   8 KB
  __shared__ float sq_s[QBL][12], bp_s[12];

  int t = threadIdx.x;
  int bid = blockIdx.x;
  int s = (bid & 7) * 128 + (bid >> 3);   // XCD x -> m-slice x
  int msl = s >> 7, qb = s & 127;
  int n0 = qb * QBL;
  int ms = msl * MSL;
  int w = t >> 6, lane = t & 63;
  int qd = t >> 2, tc = t & 3;
  int cc = lane & 31, seg = lane >> 5;
  int h0 = w * 3;

  #pragma unroll
  for (int i = 0; i < 6; i++) {
    int fi = i * 256 + t; int h = fi >> 7, d = fi & 127;
    wp_s[h * 128 + d] = Wp[d * 12 + h];
  }
  for (int idx = t; idx < QBL * 12 * 12; idx += 256) {
    int r = idx / 144, rem = idx % 144, h = rem / 12, c4 = rem % 12;
    float4 val;
    if (c4 < 8)       val = *(const float4*)&q[(n0 + r) * C + h * 32 + c4 * 4];
    else if (c4 < 11) val = *(const float4*)&qg[(n0 + r) * HP + h * 12 + (c4 - 8) * 4];
    else              val = make_float4(0.f, 0.f, 0.f, 0.f);
    val.x *= SCALING; val.y *= SCALING; val.z *= SCALING; val.w *= SCALING;
    *(float4*)&qc_s[r][h][c4 * 4] = val;
  }
  if (t < QBL * 12) sq_s[t / 12][t % 12] = sq[(n0 + t / 12) * 12 + t % 12];
  if (t < 12) bp_s[t] = bp[t];
  __syncthreads();

  const float4* wp4 = (const float4*)wp_s;
  const float4* kcT4 = (const float4*)kcT;
  float lsum[QBL][3] = {};
  float o[QBL][3] = {};

  #pragma unroll
  for (int sub = 0; sub < 2; sub++) {
    int m0 = ms + sub * 64;
    // ---- PB phase: quad qd owns key m0+qd, loops the 8 q-rows ----
    {
      float skr[12];
      #pragma unroll
      for (int i = 0; i < 3; i++)
        *(float4*)&skr[i * 4] = *(const float4*)&sknh[(m0 + qd) * 12 + i * 4];
      const float4* rpr = pair4 + ((long)n0 * N + m0 + qd) * 32;
      #pragma unroll
      for (int r = 0; r < QBL; r++) {
        float acc[12] = {};
        #pragma unroll
        for (int i = 0; i < 8; i++) {
          float4 a = rpr[i * 4 + tc];
          #pragma unroll
          for (int h = 0; h < 12; h++) {
            float4 ww = wp4[h * 32 + i * 4 + tc];
            acc[h] = fmaf(a.x, ww.x, acc[h]);
            acc[h] = fmaf(a.y, ww.y, acc[h]);
            acc[h] = fmaf(a.z, ww.z, acc[h]);
            acc[h] = fmaf(a.w, ww.w, acc[h]);
          }
        }
        #pragma unroll
        for (int h = 0; h < 12; h++) {
          acc[h] += __shfl_xor(acc[h], 1);
          acc[h] += __shfl_xor(acc[h], 2);
        }
        #pragma unroll
        for (int j = 0; j < 3; j++) {       // lane tc writes heads tc*3..tc*3+2
          int h = tc * 3 + j;
          pbx[r][h][qd] = acc[h] + bp_s[h]
                        - 0.5f * SCALING * (sq_s[r][h] + skr[h]);
        }
        rpr += N * 32;
      }
    }
    __syncthreads();                        // pbx complete
    // ---- QK + AV, per head (wave-private p_s, no barrier inside) ----
    #pragma unroll
    for (int hh = 0; hh < 3; hh++) {
      int h = h0 + hh;
      float4 kr[11];
      #pragma unroll
      for (int c4 = 0; c4 < 11; c4++)
        kr[c4] = kcT4[(long)(h * 12 + c4) * N + m0 + lane];
      #pragma unroll
      for (int r = 0; r < QBL; r++) {
        float L = pbx[r][h][lane];
        #pragma unroll
        for (int c4 = 0; c4 < 11; c4++) {
          float4 qv = *(const float4*)&qc_s[r][h][c4 * 4];
          L = fmaf(qv.x, kr[c4].x, L);
          L = fmaf(qv.y, kr[c4].y, L);
          L = fmaf(qv.z, kr[c4].z, L);
          L = fmaf(qv.w, kr[c4].w, L);
        }
        float p = __expf(L);                // max-free (validated r7/r8)
        lsum[r][hh] += p;
        p_s[w][r][lane] = p;
      }
      float vr[32];
      #pragma unroll
      for (int jj = 0; jj < 32; jj++)
        vr[jj] = v[(m0 + seg * 32 + jj) * C + h * 32 + cc];
      #pragma unroll
      for (int r = 0; r < QBL; r++) {
        float ax = 0.f, ay = 0.f, az = 0.f, aw = 0.f;
        const float4* p4 = (const float4*)&p_s[w][r][seg * 32];
        #pragma unroll
        for (int j4 = 0; j4 < 8; j4++) {
          float4 pv = p4[j4];
          ax = fmaf(pv.x, vr[j4 * 4],     ax);
          ay = fmaf(pv.y, vr[j4 * 4 + 1], ay);
          az = fmaf(pv.z, vr[j4 * 4 + 2], az);
          aw = fmaf(pv.w, vr[j4 * 4 + 3], aw);
        }
        o[r][hh] += (ax + ay) + (az + aw);
      }
    }
    __syncthreads();                        // pbx reads done before overwrite
  }

  // ---- epilogue: combine halves, reduce lsum, write partials ----
  #pragma unroll
  for (int r = 0; r < QBL; r++)
    #pragma unroll
    for (int hh = 0; hh < 3; hh++) {
      o[r][hh] += __shfl_xor(o[r][hh], 32);
      float ls = lsum[r][hh];
      #pragma unroll
      for (int off = 32; off; off >>= 1) ls += __shfl_xor(ls, off);
      lsum[r][hh] = ls;
    }
  #pragma unroll
  for (int r = 0; r < QBL; r++)
    #pragma unroll
    for (int hh = 0; hh < 3; hh++) {
      if (lane < 32)
        opart[((long)msl * N + n0 + r) * C + (h0 + hh) * 32 + lane] = o[r][hh];
      if (lane == 0)
        lpart[((long)msl * N + n0 + r) * 12 + h0 + hh] = lsum[r][hh];
    }
}

// ---------------- K2b: combine partial slices ----------------
__global__ __launch_bounds__(384) void k_red(
    const float* __restrict__ opart, const float* __restrict__ lpart,
    float* __restrict__ wt)
{
  int n = blockIdx.x, t = threadIdx.x;
  int h = t >> 5;
  float os = 0.f, ls = 0.f;
  #pragma unroll
  for (int s = 0; s < NSLICE; s++) {
    os += opart[((long)s * N + n) * C + t];
    ls += lpart[((long)s * N + n) * 12 + h];
  }
  wt[n * C + t] = os / ls;
}

// ---------------- K4: output GEMM + residual + LayerNorm (r8, unchanged) ----------------
__global__ __launch_bounds__(384) void k_out(
    const float* __restrict__ wt, const float* __restrict__ Wo,
    const float* __restrict__ bo, const float* __restrict__ single,
    const float* __restrict__ gamma, const float* __restrict__ beta,
    float* __restrict__ out)
{
  __shared__ __align__(16) float wt_s[4 * C];
  __shared__ __align__(16) float red[4][2][6];
  int t = threadIdx.x, n0 = blockIdx.x * 4;
  for (int idx = t; idx < 4 * C; idx += 384) wt_s[idx] = wt[n0 * C + idx];
  __syncthreads();
  float acc[4] = {};
  for (int ck = 0; ck < C; ck++) {
    float w = Wo[ck * C + t];
    #pragma unroll
    for (int i = 0; i < 4; i++) acc[i] = fmaf(wt_s[i * C + ck], w, acc[i]);
  }
  float x[4], bov = bo[t];
  #pragma unroll
  for (int i = 0; i < 4; i++) x[i] = single[(n0 + i) * C + t] + acc[i] + bov;
  int wid = t >> 6, lane = t & 63;
  #pragma unroll
  for (int i = 0; i < 4; i++) {
    float s = x[i], s2 = x[i] * x[i];
    #pragma unroll
    for (int off = 32; off; off >>= 1) { s += __shfl_xor(s, off); s2 += __shfl_xor(s2, off); }
    if (lane == 0) { red[i][0][wid] = s; red[i][1][wid] = s2; }
  }
  __syncthreads();
  float gv = gamma[t], bv = beta[t];
  #pragma unroll
  for (int i = 0; i < 4; i++) {
    float S = 0.f, S2 = 0.f;
    #pragma unroll
    for (int w = 0; w < 6; w++) { S += red[i][0][w]; S2 += red[i][1][w]; }
    float mu = S * (1.0f / C);
    float var = S2 * (1.0f / C) - mu * mu;
    out[(n0 + i) * C + t] = (x[i] - mu) * rsqrtf(var + LN_EPS) * gv + bv;
  }
}

extern "C" void kernel_launch(void* const* d_in, const int* in_sizes, int n_in,
                              void* d_out, int out_size, void* d_ws, size_t ws_size,
                              hipStream_t stream) {
  const float* single = (const float*)d_in[0];
  const float* pair   = (const float*)d_in[1];
  const float* rot    = (const float*)d_in[2];
  const float* Wq  = (const float*)d_in[4];  const float* bq  = (const float*)d_in[5];
  const float* Wk  = (const float*)d_in[6];  const float* bk  = (const float*)d_in[7];
  const float* Wv  = (const float*)d_in[8];  const float* bv  = (const float*)d_in[9];
  const float* Wp  = (const float*)d_in[10]; const float* bp  = (const float*)d_in[11];
  const float* Wpq = (const float*)d_in[12]; const float* bpq = (const float*)d_in[13];
  const float* Wpk = (const float*)d_in[14]; const float* bpk = (const float*)d_in[15];
  const float* Wo  = (const float*)d_in[16]; const float* bo  = (const float*)d_in[17];
  const float* gamma = (const float*)d_in[18]; const float* beta = (const float*)d_in[19];

  float* ws    = (float*)d_ws;
  float* q     = ws;                         // [N][C]
  float* v     = q + N * C;                  // [N][C]
  float* qp    = v + N * C;                  // [N][HP]
  float* kp    = qp + N * HP;                // [N][HP]
  float* qg    = kp + N * HP;                // [N][HP]
  float* kcg   = qg + N * HP;                // [12][N][48]
  float* sq    = kcg + 12L * N * 48;         // [N][12]
  float* sknh  = sq + N * H;                 // [N][12]
  float* wt    = sknh + N * H;               // [N][C]
  float* kcT   = wt + N * C;                 // [12][12][N][4]
  float* opart = kcT + 12L * 12 * N * 4;     // [8][N][C]
  float* lpart = opart + (long)NSLICE * N * C;  // [8][N][12]

  k_qkv<<<dim3(30, 16), 256, 0, stream>>>(single, Wq, bq, Wk, bk, Wv, bv,
                                          Wpq, bpq, Wpk, bpk, q, kcg, v, qp, kp);
  k_rot<<<N, 256, 0, stream>>>(qp, kp, rot, qg, kcg, sq, sknh);
  k_tr<<<192, 256, 0, stream>>>(kcg, kcT);
  k_fused<<<1024, 256, 0, stream>>>((const float4*)pair, Wp, bp, sq, sknh,
                                    q, qg, kcT, v, opart, lpart);
  k_red<<<N, 384, 0, stream>>>(opart, lpart, wt);
  k_out<<<256, 384, 0, stream>>>(wt, Wo, bo, single, gamma, beta, (float*)d_out);
}

// Round 13
// 262.206 us; speedup vs baseline: 7.6951x; 7.6951x over previous
//
#include <hip/hip_runtime.h>
#include <math.h>

#define N 1024
#define C 384
#define H 12
#define DP 128
#define HP 144
#define MT 64   // keys per tile
#define NT 16   // tiles
#define RW 2    // q-rows per wave
#define QBL 8   // q-rows per block (4 waves x 2 rows)
#define SCALING 0.17677669529663687f
#define LN_EPS 1e-5f

// ---------------- K1: fused projections GEMM (r8, unchanged) ----------------
__global__ __launch_bounds__(256) void k_qkv(
    const float* __restrict__ single,
    const float* __restrict__ Wq, const float* __restrict__ bq,
    const float* __restrict__ Wk, const float* __restrict__ bk,
    const float* __restrict__ Wv, const float* __restrict__ bv,
    const float* __restrict__ Wpq, const float* __restrict__ bpq,
    const float* __restrict__ Wpk, const float* __restrict__ bpk,
    float* __restrict__ q, float* __restrict__ kcg, float* __restrict__ v,
    float* __restrict__ qp, float* __restrict__ kp)
{
  __shared__ __align__(16) float A_s[64 * 33];
  __shared__ __align__(16) float B_s[32 * 48];
  int t = threadIdx.x;
  int nt = blockIdx.x, mt = blockIdx.y;
  int m0 = mt * 64;
  const float* W; const float* bias; int ld, kind, cb;
  if (nt < 8)       { W = Wq;  bias = bq;  ld = C;  cb = nt * 48;        kind = 0; }
  else if (nt < 16) { W = Wk;  bias = bk;  ld = C;  cb = (nt - 8) * 48;  kind = 1; }
  else if (nt < 24) { W = Wv;  bias = bv;  ld = C;  cb = (nt - 16) * 48; kind = 2; }
  else if (nt < 27) { W = Wpq; bias = bpq; ld = HP; cb = (nt - 24) * 48; kind = 3; }
  else              { W = Wpk; bias = bpk; ld = HP; cb = (nt - 27) * 48; kind = 4; }
  int tr = t >> 4, tc = t & 15;
  float acc[4][3] = {};
  for (int k0 = 0; k0 < C; k0 += 32) {
    if (k0) __syncthreads();
    #pragma unroll
    for (int i = 0; i < 8; i++) {
      int fi = i * 256 + t; int row = fi >> 5, col = fi & 31;
      A_s[row * 33 + col] = single[(m0 + row) * C + k0 + col];
    }
    #pragma unroll
    for (int i = 0; i < 6; i++) {
      int fi = i * 256 + t; int row = fi / 48, col = fi % 48;
      B_s[row * 48 + col] = W[(k0 + row) * ld + cb + col];
    }
    __syncthreads();
    #pragma unroll
    for (int k = 0; k < 32; k++) {
      float a[4], b[3];
      #pragma unroll
      for (int r = 0; r < 4; r++) a[r] = A_s[(tr * 4 + r) * 33 + k];
      #pragma unroll
      for (int c = 0; c < 3; c++) b[c] = B_s[k * 48 + tc * 3 + c];
      #pragma unroll
      for (int r = 0; r < 4; r++)
        #pragma unroll
        for (int c = 0; c < 3; c++) acc[r][c] = fmaf(a[r], b[c], acc[r][c]);
    }
  }
  #pragma unroll
  for (int c = 0; c < 3; c++) {
    int col = cb + tc * 3 + c;
    float bb = bias[col];
    #pragma unroll
    for (int r = 0; r < 4; r++) {
      int row = m0 + tr * 4 + r;
      float val = acc[r][c] + bb;
      if (kind == 0)      q[row * C + col] = val;
      else if (kind == 1) kcg[((col >> 5) * N + row) * 48 + (col & 31)] = val;
      else if (kind == 2) v[row * C + col] = val;
      else if (kind == 3) qp[row * HP + col] = val;
      else                kp[row * HP + col] = val;
    }
  }
}

// ---------------- K1b: rotate points, sq/sk sums (r8, unchanged) ----------------
__global__ __launch_bounds__(256) void k_rot(
    const float* __restrict__ qp, const float* __restrict__ kp,
    const float* __restrict__ rot,
    float* __restrict__ qg, float* __restrict__ kcg,
    float* __restrict__ sq, float* __restrict__ sknh)
{
  __shared__ __align__(16) float qp_s[HP], kp_s[HP], rot_s[9], q2_s[HP], k2_s[HP];
  int n = blockIdx.x, t = threadIdx.x;
  if (t < HP) { qp_s[t] = qp[n * HP + t]; kp_s[t] = kp[n * HP + t]; }
  if (t < 9)  rot_s[t] = rot[n * 9 + t];
  __syncthreads();
  if (t < HP) {
    int h = t / 12, r12 = t % 12, y = r12 >> 2, p = r12 & 3;
    float qgv = rot_s[y*3] * qp_s[h*12 + p] + rot_s[y*3+1] * qp_s[h*12 + 4 + p]
              + rot_s[y*3+2] * qp_s[h*12 + 8 + p];
    float kgv = rot_s[y*3] * kp_s[h*12 + p] + rot_s[y*3+1] * kp_s[h*12 + 4 + p]
              + rot_s[y*3+2] * kp_s[h*12 + 8 + p];
    qg[n * HP + t] = qgv;
    kcg[(h * N + n) * 48 + 32 + r12] = kgv;
    q2_s[t] = qgv * qgv; k2_s[t] = kgv * kgv;
  }
  if (t < 48) kcg[((t >> 2) * N + n) * 48 + 44 + (t & 3)] = 0.f;  // zero pad
  __syncthreads();
  if (t < H) {
    float s1 = 0.f, s2 = 0.f;
    #pragma unroll
    for (int e = 0; e < 12; e++) { s1 += q2_s[t * 12 + e]; s2 += k2_s[t * 12 + e]; }
    sq[n * H + t] = s1; sknh[n * H + t] = s2;
  }
}

// ---------------- K2: pair bias GEMM + rank-1 fold (r8, unchanged) ----------------
__global__ __launch_bounds__(256) void k_pb(
    const float4* __restrict__ pair4, const float* __restrict__ Wp,
    const float* __restrict__ bp, const float* __restrict__ sq,
    const float* __restrict__ sknh, float* __restrict__ pb)
{
  __shared__ __align__(16) float wp_s[12 * 128];   // [h][d]
  __shared__ __align__(16) float ob_s[12][128];
  __shared__ float sq_s[12], bp_s[12];
  int t = threadIdx.x;
  int bid = blockIdx.x;
  int n = bid >> 3;                 // 8 blocks of 128 m per n-row
  int m0 = (bid & 7) * 128;
  #pragma unroll
  for (int i = 0; i < 6; i++) {
    int fi = i * 256 + t; int h = fi >> 7, d = fi & 127;
    wp_s[h * 128 + d] = Wp[d * 12 + h];
  }
  if (t < 12) { sq_s[t] = sq[n * 12 + t]; bp_s[t] = bp[t]; }
  __syncthreads();
  int tc = t & 3, rid = t >> 2;                    // rows rid and 64+rid
  long rowA = (long)n * N + m0 + rid;
  const float4* rpA = pair4 + rowA * 32;
  const float4* rpB = rpA + 64 * 32;
  const float4* w4 = (const float4*)wp_s;          // [h][32]
  float accA[12] = {}, accB[12] = {};
  #pragma unroll
  for (int i = 0; i < 8; i++) {
    float4 a = rpA[i * 4 + tc];
    float4 b = rpB[i * 4 + tc];
    #pragma unroll
    for (int h = 0; h < 12; h++) {
      float4 w = w4[h * 32 + i * 4 + tc];
      accA[h] = fmaf(a.x, w.x, accA[h]);
      accA[h] = fmaf(a.y, w.y, accA[h]);
      accA[h] = fmaf(a.z, w.z, accA[h]);
      accA[h] = fmaf(a.w, w.w, accA[h]);
      accB[h] = fmaf(b.x, w.x, accB[h]);
      accB[h] = fmaf(b.y, w.y, accB[h]);
      accB[h] = fmaf(b.z, w.z, accB[h]);
      accB[h] = fmaf(b.w, w.w, accB[h]);
    }
  }
  #pragma unroll
  for (int h = 0; h < 12; h++) {
    accA[h] += __shfl_xor(accA[h], 1);
    accA[h] += __shfl_xor(accA[h], 2);
    accB[h] += __shfl_xor(accB[h], 1);
    accB[h] += __shfl_xor(accB[h], 2);
  }
  if (tc == 0) {
    float skrA[12], skrB[12];
    #pragma unroll
    for (int i = 0; i < 3; i++) {
      *(float4*)&skrA[i * 4] = *(const float4*)&sknh[(m0 + rid) * 12 + i * 4];
      *(float4*)&skrB[i * 4] = *(const float4*)&sknh[(m0 + 64 + rid) * 12 + i * 4];
    }
    #pragma unroll
    for (int h = 0; h < 12; h++) {
      ob_s[h][rid]      = accA[h] + bp_s[h] - 0.5f * SCALING * (sq_s[h] + skrA[h]);
      ob_s[h][64 + rid] = accB[h] + bp_s[h] - 0.5f * SCALING * (sq_s[h] + skrB[h]);
    }
  }
  __syncthreads();
  #pragma unroll
  for (int i = 0; i < 6; i++) {
    int idx = i * 256 + t; int h = idx >> 7, r = idx & 127;
    pb[(long)h * (N * (long)N) + (long)n * N + m0 + r] = ob_s[h][r];
  }
}

// ---------------- K3: flash attention v13 = r8 staging + lane=m AV ----------------
// QK identical to r8 (lane=m, swizzled kc_s, qc broadcasts, max-free exp).
// AV: p stays in registers; lane m accumulates o_[r][c] (64 private VGPRs)
// from v_s[m][c] (natural layout, XOR-swizzled, 8 b128 reads). Eliminates
// p_s entirely (16 writes + 32 broadcasts) and the 16-scalar-write V
// transpose. Epilogue: r10-proven select+shfl butterfly transpose-reduce.
__global__ __launch_bounds__(256) void k_attn(
    const float* __restrict__ q, const float* __restrict__ qg,
    const float* __restrict__ kcg, const float* __restrict__ v,
    const float* __restrict__ pb, float* __restrict__ wt)
{
  __shared__ __align__(16) float kc_s[64 * 64];    // [m][12 chunks], XOR (m&7)
  __shared__ __align__(16) float v_s[64 * 32];     // [m][8 chunks],  XOR (m&7)
  __shared__ __align__(16) float qc_s[QBL][48];    // S-prescaled [q|qg|0]

  int t = threadIdx.x;
  int bid = blockIdx.x;
  int s = (bid & 7) * 192 + (bid >> 3);   // 1.5 heads per XCD
  int h = s >> 7, qb = s & 127;
  int q0 = qb * QBL;
  int w = t >> 6, lane = t & 63;
  long pbbase = (long)h * (N * (long)N);
  const float* kch = kcg + (long)h * N * 48;
  int hc32 = h * 32;
  int mr = t >> 3, c4v = t & 7;
  int w2 = w * 2;

  float4 pk0, pk1, pk2, pv0, pv1;
  float pb_cur[RW], pb_nxt[RW];

#define STAGE_LOAD(M0) \
  { int f0 = t, f1 = 256 + t, f2 = 512 + t; \
    pk0 = *(const float4*)&kch[((M0) + f0 / 12) * 48 + (f0 % 12) * 4]; \
    pk1 = *(const float4*)&kch[((M0) + f1 / 12) * 48 + (f1 % 12) * 4]; \
    pk2 = *(const float4*)&kch[((M0) + f2 / 12) * 48 + (f2 % 12) * 4]; \
    pv0 = *(const float4*)&v[((M0) + mr) * C + hc32 + c4v * 4]; \
    pv1 = *(const float4*)&v[((M0) + 32 + mr) * C + hc32 + c4v * 4]; }

#define ST_KC(F, VAL) \
  { int row_ = (F) / 12, c4_ = (F) % 12; \
    *(float4*)&kc_s[row_ * 64 + ((c4_ ^ (row_ & 7)) << 2)] = VAL; }
#define ST_V(MM, VAL) \
  *(float4*)&v_s[(MM) * 32 + ((c4v ^ ((MM) & 7)) << 2)] = VAL;

#define STAGE_WRITE() \
  { ST_KC(t, pk0) ST_KC(256 + t, pk1) ST_KC(512 + t, pk2) \
    ST_V(mr, pv0) ST_V(32 + mr, pv1) }

  // prologue: stage tile 0, build qc, load pb chunk 0
  STAGE_LOAD(0);
  #pragma unroll
  for (int r = 0; r < RW; r++)
    pb_cur[r] = pb[pbbase + (long)(q0 + w2 + r) * N + lane];
  if (t < QBL * 12) {
    int r = t / 12, c4 = t % 12;
    float4 val;
    if (c4 < 8)       val = *(const float4*)&q[(q0 + r) * C + hc32 + c4 * 4];
    else if (c4 < 11) val = *(const float4*)&qg[(q0 + r) * HP + h * 12 + (c4 - 8) * 4];
    else              val = make_float4(0.f, 0.f, 0.f, 0.f);
    val.x *= SCALING; val.y *= SCALING; val.z *= SCALING; val.w *= SCALING;
    *(float4*)&qc_s[r][c4 * 4] = val;
  }
  STAGE_WRITE();
  __syncthreads();

  float lsum0 = 0.f, lsum1 = 0.f;
  float o_[2][32] = {};

  for (int tile = 0; tile < NT; tile++) {
    int m0 = tile * MT;
    if (tile < NT - 1) {
      STAGE_LOAD(m0 + MT);
      #pragma unroll
      for (int r = 0; r < RW; r++)
        pb_nxt[r] = pb[pbbase + (long)(q0 + w2 + r) * N + m0 + MT + lane];
    }
    // ---- QK (lane=m): 11 swizzled b128 + 22 broadcasts ----
    float L0 = pb_cur[0], L1 = pb_cur[1];
    #pragma unroll
    for (int c4 = 0; c4 < 11; c4++) {
      float4 kv = *(const float4*)&kc_s[lane * 64 + ((c4 ^ (lane & 7)) << 2)];
      float4 qv0 = *(const float4*)&qc_s[w2][c4 * 4];
      float4 qv1 = *(const float4*)&qc_s[w2 + 1][c4 * 4];
      L0 = fmaf(qv0.x, kv.x, L0); L0 = fmaf(qv0.y, kv.y, L0);
      L0 = fmaf(qv0.z, kv.z, L0); L0 = fmaf(qv0.w, kv.w, L0);
      L1 = fmaf(qv1.x, kv.x, L1); L1 = fmaf(qv1.y, kv.y, L1);
      L1 = fmaf(qv1.z, kv.z, L1); L1 = fmaf(qv1.w, kv.w, L1);
    }
    float p0 = __expf(L0), p1 = __expf(L1);   // max-free (validated r7/r8)
    lsum0 += p0; lsum1 += p1;
    // ---- AV (lane=m): 8 swizzled b128, p in registers, o_ private ----
    #pragma unroll
    for (int c4 = 0; c4 < 8; c4++) {
      float4 vv = *(const float4*)&v_s[lane * 32 + ((c4 ^ (lane & 7)) << 2)];
      o_[0][c4*4+0] = fmaf(p0, vv.x, o_[0][c4*4+0]);
      o_[0][c4*4+1] = fmaf(p0, vv.y, o_[0][c4*4+1]);
      o_[0][c4*4+2] = fmaf(p0, vv.z, o_[0][c4*4+2]);
      o_[0][c4*4+3] = fmaf(p0, vv.w, o_[0][c4*4+3]);
      o_[1][c4*4+0] = fmaf(p1, vv.x, o_[1][c4*4+0]);
      o_[1][c4*4+1] = fmaf(p1, vv.y, o_[1][c4*4+1]);
      o_[1][c4*4+2] = fmaf(p1, vv.z, o_[1][c4*4+2]);
      o_[1][c4*4+3] = fmaf(p1, vv.w, o_[1][c4*4+3]);
    }
    __syncthreads();                 // all reads of kc_s/v_s done
    if (tile < NT - 1) {
      STAGE_WRITE();
      #pragma unroll
      for (int r = 0; r < RW; r++) pb_cur[r] = pb_nxt[r];
    }
    __syncthreads();                 // writes visible for next tile
  }

  #pragma unroll
  for (int off = 32; off; off >>= 1) {
    lsum0 += __shfl_xor(lsum0, off);
    lsum1 += __shfl_xor(lsum1, off);
  }
  // butterfly transpose-reduce (r10-proven): col c sum lands at lane c (c<32)
  #pragma unroll
  for (int r = 0; r < 2; r++) {
    float c16[16], c8[8], c4a[4], c2[2], c1;
    int b = lane & 1;
    #pragma unroll
    for (int j = 0; j < 16; j++) {
      float keep = b ? o_[r][2*j+1] : o_[r][2*j];
      float send = b ? o_[r][2*j]   : o_[r][2*j+1];
      c16[j] = keep + __shfl_xor(send, 1);
    }
    b = lane & 2;
    #pragma unroll
    for (int j = 0; j < 8; j++) {
      float keep = b ? c16[2*j+1] : c16[2*j];
      float send = b ? c16[2*j]   : c16[2*j+1];
      c8[j] = keep + __shfl_xor(send, 2);
    }
    b = lane & 4;
    #pragma unroll
    for (int j = 0; j < 4; j++) {
      float keep = b ? c8[2*j+1] : c8[2*j];
      float send = b ? c8[2*j]   : c8[2*j+1];
      c4a[j] = keep + __shfl_xor(send, 4);
    }
    b = lane & 8;
    #pragma unroll
    for (int j = 0; j < 2; j++) {
      float keep = b ? c4a[2*j+1] : c4a[2*j];
      float send = b ? c4a[2*j]   : c4a[2*j+1];
      c2[j] = keep + __shfl_xor(send, 8);
    }
    b = lane & 16;
    {
      float keep = b ? c2[1] : c2[0];
      float send = b ? c2[0] : c2[1];
      c1 = keep + __shfl_xor(send, 16);
    }
    c1 += __shfl_xor(c1, 32);
    float ls = (r == 0) ? lsum0 : lsum1;
    if (lane < 32) wt[(q0 + w2 + r) * C + hc32 + lane] = c1 / ls;
  }
#undef STAGE_LOAD
#undef STAGE_WRITE
#undef ST_KC
#undef ST_V
}

// ---------------- K4: output GEMM + residual + LayerNorm (r8, unchanged) ----------------
__global__ __launch_bounds__(384) void k_out(
    const float* __restrict__ wt, const float* __restrict__ Wo,
    const float* __restrict__ bo, const float* __restrict__ single,
    const float* __restrict__ gamma, const float* __restrict__ beta,
    float* __restrict__ out)
{
  __shared__ __align__(16) float wt_s[4 * C];
  __shared__ __align__(16) float red[4][2][6];
  int t = threadIdx.x, n0 = blockIdx.x * 4;
  for (int idx = t; idx < 4 * C; idx += 384) wt_s[idx] = wt[n0 * C + idx];
  __syncthreads();
  float acc[4] = {};
  for (int ck = 0; ck < C; ck++) {
    float w = Wo[ck * C + t];
    #pragma unroll
    for (int i = 0; i < 4; i++) acc[i] = fmaf(wt_s[i * C + ck], w, acc[i]);
  }
  float x[4], bov = bo[t];
  #pragma unroll
  for (int i = 0; i < 4; i++) x[i] = single[(n0 + i) * C + t] + acc[i] + bov;
  int wid = t >> 6, lane = t & 63;
  #pragma unroll
  for (int i = 0; i < 4; i++) {
    float s = x[i], s2 = x[i] * x[i];
    #pragma unroll
    for (int off = 32; off; off >>= 1) { s += __shfl_xor(s, off); s2 += __shfl_xor(s2, off); }
    if (lane == 0) { red[i][0][wid] = s; red[i][1][wid] = s2; }
  }
  __syncthreads();
  float gv = gamma[t], bv = beta[t];
  #pragma unroll
  for (int i = 0; i < 4; i++) {
    float S = 0.f, S2 = 0.f;
    #pragma unroll
    for (int w = 0; w < 6; w++) { S += red[i][0][w]; S2 += red[i][1][w]; }
    float mu = S * (1.0f / C);
    float var = S2 * (1.0f / C) - mu * mu;
    out[(n0 + i) * C + t] = (x[i] - mu) * rsqrtf(var + LN_EPS) * gv + bv;
  }
}

extern "C" void kernel_launch(void* const* d_in, const int* in_sizes, int n_in,
                              void* d_out, int out_size, void* d_ws, size_t ws_size,
                              hipStream_t stream) {
  const float* single = (const float*)d_in[0];
  const float* pair   = (const float*)d_in[1];
  const float* rot    = (const float*)d_in[2];
  const float* Wq  = (const float*)d_in[4];  const float* bq  = (const float*)d_in[5];
  const float* Wk  = (const float*)d_in[6];  const float* bk  = (const float*)d_in[7];
  const float* Wv  = (const float*)d_in[8];  const float* bv  = (const float*)d_in[9];
  const float* Wp  = (const float*)d_in[10]; const float* bp  = (const float*)d_in[11];
  const float* Wpq = (const float*)d_in[12]; const float* bpq = (const float*)d_in[13];
  const float* Wpk = (const float*)d_in[14]; const float* bpk = (const float*)d_in[15];
  const float* Wo  = (const float*)d_in[16]; const float* bo  = (const float*)d_in[17];
  const float* gamma = (const float*)d_in[18]; const float* beta = (const float*)d_in[19];

  float* ws   = (float*)d_ws;
  float* pb   = ws;                          // [12][N*N]
  float* q    = pb + 12L * N * N;            // [N][C]
  float* v    = q + N * C;                   // [N][C]
  float* qp   = v + N * C;                   // [N][HP]
  float* kp   = qp + N * HP;                 // [N][HP]
  float* qg   = kp + N * HP;                 // [N][HP]
  float* kcg  = qg + N * HP;                 // [12][N][48]
  float* sq   = kcg + 12L * N * 48;          // [N][12]
  float* sknh = sq + N * H;                  // [N][12]
  float* wt   = sknh + N * H;                // [N][C]

  k_qkv<<<dim3(30, 16), 256, 0, stream>>>(single, Wq, bq, Wk, bk, Wv, bv,
                                          Wpq, bpq, Wpk, bpk, q, kcg, v, qp, kp);
  k_rot<<<N, 256, 0, stream>>>(qp, kp, rot, qg, kcg, sq, sknh);
  k_pb<<<8192, 256, 0, stream>>>((const float4*)pair, Wp, bp, sq, sknh, pb);
  k_attn<<<1536, 256, 0, stream>>>(q, qg, kcg, v, pb, wt);
  k_out<<<256, 384, 0, stream>>>(wt, Wo, bo, single, gamma, beta, (float*)d_out);
}

// Round 14
// 257.359 us; speedup vs baseline: 7.8400x; 1.0188x over previous
//
#include <hip/hip_runtime.h>
#include <math.h>

#define N 1024
#define C 384
#define H 12
#define DP 128
#define HP 144
#define MT 64   // keys per tile
#define NT 16   // tiles
#define RW 2    // q-rows per wave
#define QBL 8   // q-rows per block (4 waves x 2 rows)
#define SCALING 0.17677669529663687f
#define LN_EPS 1e-5f

// ---------------- K1: fused projections GEMM (r8, unchanged) ----------------
__global__ __launch_bounds__(256) void k_qkv(
    const float* __restrict__ single,
    const float* __restrict__ Wq, const float* __restrict__ bq,
    const float* __restrict__ Wk, const float* __restrict__ bk,
    const float* __restrict__ Wv, const float* __restrict__ bv,
    const float* __restrict__ Wpq, const float* __restrict__ bpq,
    const float* __restrict__ Wpk, const float* __restrict__ bpk,
    float* __restrict__ q, float* __restrict__ kcg, float* __restrict__ v,
    float* __restrict__ qp, float* __restrict__ kp)
{
  __shared__ __align__(16) float A_s[64 * 33];
  __shared__ __align__(16) float B_s[32 * 48];
  int t = threadIdx.x;
  int nt = blockIdx.x, mt = blockIdx.y;
  int m0 = mt * 64;
  const float* W; const float* bias; int ld, kind, cb;
  if (nt < 8)       { W = Wq;  bias = bq;  ld = C;  cb = nt * 48;        kind = 0; }
  else if (nt < 16) { W = Wk;  bias = bk;  ld = C;  cb = (nt - 8) * 48;  kind = 1; }
  else if (nt < 24) { W = Wv;  bias = bv;  ld = C;  cb = (nt - 16) * 48; kind = 2; }
  else if (nt < 27) { W = Wpq; bias = bpq; ld = HP; cb = (nt - 24) * 48; kind = 3; }
  else              { W = Wpk; bias = bpk; ld = HP; cb = (nt - 27) * 48; kind = 4; }
  int tr = t >> 4, tc = t & 15;
  float acc[4][3] = {};
  for (int k0 = 0; k0 < C; k0 += 32) {
    if (k0) __syncthreads();
    #pragma unroll
    for (int i = 0; i < 8; i++) {
      int fi = i * 256 + t; int row = fi >> 5, col = fi & 31;
      A_s[row * 33 + col] = single[(m0 + row) * C + k0 + col];
    }
    #pragma unroll
    for (int i = 0; i < 6; i++) {
      int fi = i * 256 + t; int row = fi / 48, col = fi % 48;
      B_s[row * 48 + col] = W[(k0 + row) * ld + cb + col];
    }
    __syncthreads();
    #pragma unroll
    for (int k = 0; k < 32; k++) {
      float a[4], b[3];
      #pragma unroll
      for (int r = 0; r < 4; r++) a[r] = A_s[(tr * 4 + r) * 33 + k];
      #pragma unroll
      for (int c = 0; c < 3; c++) b[c] = B_s[k * 48 + tc * 3 + c];
      #pragma unroll
      for (int r = 0; r < 4; r++)
        #pragma unroll
        for (int c = 0; c < 3; c++) acc[r][c] = fmaf(a[r], b[c], acc[r][c]);
    }
  }
  #pragma unroll
  for (int c = 0; c < 3; c++) {
    int col = cb + tc * 3 + c;
    float bb = bias[col];
    #pragma unroll
    for (int r = 0; r < 4; r++) {
      int row = m0 + tr * 4 + r;
      float val = acc[r][c] + bb;
      if (kind == 0)      q[row * C + col] = val;
      else if (kind == 1) kcg[((col >> 5) * N + row) * 48 + (col & 31)] = val;
      else if (kind == 2) v[row * C + col] = val;
      else if (kind == 3) qp[row * HP + col] = val;
      else                kp[row * HP + col] = val;
    }
  }
}

// ---------------- K1b: rotate points, sq/sk sums (r8, unchanged) ----------------
__global__ __launch_bounds__(256) void k_rot(
    const float* __restrict__ qp, const float* __restrict__ kp,
    const float* __restrict__ rot,
    float* __restrict__ qg, float* __restrict__ kcg,
    float* __restrict__ sq, float* __restrict__ sknh)
{
  __shared__ __align__(16) float qp_s[HP], kp_s[HP], rot_s[9], q2_s[HP], k2_s[HP];
  int n = blockIdx.x, t = threadIdx.x;
  if (t < HP) { qp_s[t] = qp[n * HP + t]; kp_s[t] = kp[n * HP + t]; }
  if (t < 9)  rot_s[t] = rot[n * 9 + t];
  __syncthreads();
  if (t < HP) {
    int h = t / 12, r12 = t % 12, y = r12 >> 2, p = r12 & 3;
    float qgv = rot_s[y*3] * qp_s[h*12 + p] + rot_s[y*3+1] * qp_s[h*12 + 4 + p]
              + rot_s[y*3+2] * qp_s[h*12 + 8 + p];
    float kgv = rot_s[y*3] * kp_s[h*12 + p] + rot_s[y*3+1] * kp_s[h*12 + 4 + p]
              + rot_s[y*3+2] * kp_s[h*12 + 8 + p];
    qg[n * HP + t] = qgv;
    kcg[(h * N + n) * 48 + 32 + r12] = kgv;
    q2_s[t] = qgv * qgv; k2_s[t] = kgv * kgv;
  }
  if (t < 48) kcg[((t >> 2) * N + n) * 48 + 44 + (t & 3)] = 0.f;  // zero pad
  __syncthreads();
  if (t < H) {
    float s1 = 0.f, s2 = 0.f;
    #pragma unroll
    for (int e = 0; e < 12; e++) { s1 += q2_s[t * 12 + e]; s2 += k2_s[t * 12 + e]; }
    sq[n * H + t] = s1; sknh[n * H + t] = s2;
  }
}

// ---------------- K2: pair bias GEMM + rank-1 fold (r8, unchanged) ----------------
__global__ __launch_bounds__(256) void k_pb(
    const float4* __restrict__ pair4, const float* __restrict__ Wp,
    const float* __restrict__ bp, const float* __restrict__ sq,
    const float* __restrict__ sknh, float* __restrict__ pb)
{
  __shared__ __align__(16) float wp_s[12 * 128];   // [h][d]
  __shared__ __align__(16) float ob_s[12][128];
  __shared__ float sq_s[12], bp_s[12];
  int t = threadIdx.x;
  int bid = blockIdx.x;
  int n = bid >> 3;                 // 8 blocks of 128 m per n-row
  int m0 = (bid & 7) * 128;
  #pragma unroll
  for (int i = 0; i < 6; i++) {
    int fi = i * 256 + t; int h = fi >> 7, d = fi & 127;
    wp_s[h * 128 + d] = Wp[d * 12 + h];
  }
  if (t < 12) { sq_s[t] = sq[n * 12 + t]; bp_s[t] = bp[t]; }
  __syncthreads();
  int tc = t & 3, rid = t >> 2;                    // rows rid and 64+rid
  long rowA = (long)n * N + m0 + rid;
  const float4* rpA = pair4 + rowA * 32;
  const float4* rpB = rpA + 64 * 32;
  const float4* w4 = (const float4*)wp_s;          // [h][32]
  float accA[12] = {}, accB[12] = {};
  #pragma unroll
  for (int i = 0; i < 8; i++) {
    float4 a = rpA[i * 4 + tc];
    float4 b = rpB[i * 4 + tc];
    #pragma unroll
    for (int h = 0; h < 12; h++) {
      float4 w = w4[h * 32 + i * 4 + tc];
      accA[h] = fmaf(a.x, w.x, accA[h]);
      accA[h] = fmaf(a.y, w.y, accA[h]);
      accA[h] = fmaf(a.z, w.z, accA[h]);
      accA[h] = fmaf(a.w, w.w, accA[h]);
      accB[h] = fmaf(b.x, w.x, accB[h]);
      accB[h] = fmaf(b.y, w.y, accB[h]);
      accB[h] = fmaf(b.z, w.z, accB[h]);
      accB[h] = fmaf(b.w, w.w, accB[h]);
    }
  }
  #pragma unroll
  for (int h = 0; h < 12; h++) {
    accA[h] += __shfl_xor(accA[h], 1);
    accA[h] += __shfl_xor(accA[h], 2);
    accB[h] += __shfl_xor(accB[h], 1);
    accB[h] += __shfl_xor(accB[h], 2);
  }
  if (tc == 0) {
    float skrA[12], skrB[12];
    #pragma unroll
    for (int i = 0; i < 3; i++) {
      *(float4*)&skrA[i * 4] = *(const float4*)&sknh[(m0 + rid) * 12 + i * 4];
      *(float4*)&skrB[i * 4] = *(const float4*)&sknh[(m0 + 64 + rid) * 12 + i * 4];
    }
    #pragma unroll
    for (int h = 0; h < 12; h++) {
      ob_s[h][rid]      = accA[h] + bp_s[h] - 0.5f * SCALING * (sq_s[h] + skrA[h]);
      ob_s[h][64 + rid] = accB[h] + bp_s[h] - 0.5f * SCALING * (sq_s[h] + skrB[h]);
    }
  }
  __syncthreads();
  #pragma unroll
  for (int i = 0; i < 6; i++) {
    int idx = i * 256 + t; int h = idx >> 7, r = idx & 127;
    pb[(long)h * (N * (long)N) + (long)n * N + m0 + r] = ob_s[h][r];
  }
}

// ---------------- K3: flash attention v14 = r13 + double-buffer (1 barrier/tile) ----------------
// Identical to r13 except kc_s/v_s are double-buffered: STAGE_WRITE targets
// buf cb^1 while compute reads buf cb, so ONE barrier per tile suffices
// (no WAR hazard). LDS 26->50 KB; residency already VGPR-limited to ~3
// blocks/CU, so occupancy unchanged and 16 barrier waits are removed.
__global__ __launch_bounds__(256) void k_attn(
    const float* __restrict__ q, const float* __restrict__ qg,
    const float* __restrict__ kcg, const float* __restrict__ v,
    const float* __restrict__ pb, float* __restrict__ wt)
{
  __shared__ __align__(16) float kc_s[2][64 * 64];  // [buf][m][12 chunks], XOR (m&7)
  __shared__ __align__(16) float v_s[2][64 * 32];   // [buf][m][8 chunks],  XOR (m&7)
  __shared__ __align__(16) float qc_s[QBL][48];     // S-prescaled [q|qg|0]

  int t = threadIdx.x;
  int bid = blockIdx.x;
  int s = (bid & 7) * 192 + (bid >> 3);   // 1.5 heads per XCD
  int h = s >> 7, qb = s & 127;
  int q0 = qb * QBL;
  int w = t >> 6, lane = t & 63;
  long pbbase = (long)h * (N * (long)N);
  const float* kch = kcg + (long)h * N * 48;
  int hc32 = h * 32;
  int mr = t >> 3, c4v = t & 7;
  int w2 = w * 2;

  float4 pk0, pk1, pk2, pv0, pv1;
  float pb_cur[RW], pb_nxt[RW];

#define STAGE_LOAD(M0) \
  { int f0 = t, f1 = 256 + t, f2 = 512 + t; \
    pk0 = *(const float4*)&kch[((M0) + f0 / 12) * 48 + (f0 % 12) * 4]; \
    pk1 = *(const float4*)&kch[((M0) + f1 / 12) * 48 + (f1 % 12) * 4]; \
    pk2 = *(const float4*)&kch[((M0) + f2 / 12) * 48 + (f2 % 12) * 4]; \
    pv0 = *(const float4*)&v[((M0) + mr) * C + hc32 + c4v * 4]; \
    pv1 = *(const float4*)&v[((M0) + 32 + mr) * C + hc32 + c4v * 4]; }

#define ST_KC(B, F, VAL) \
  { int row_ = (F) / 12, c4_ = (F) % 12; \
    *(float4*)&kc_s[B][row_ * 64 + ((c4_ ^ (row_ & 7)) << 2)] = VAL; }
#define ST_V(B, MM, VAL) \
  *(float4*)&v_s[B][(MM) * 32 + ((c4v ^ ((MM) & 7)) << 2)] = VAL;

#define STAGE_WRITE(B) \
  { ST_KC(B, t, pk0) ST_KC(B, 256 + t, pk1) ST_KC(B, 512 + t, pk2) \
    ST_V(B, mr, pv0) ST_V(B, 32 + mr, pv1) }

  // prologue: stage tile 0 -> buf 0, build qc, load pb chunk 0
  STAGE_LOAD(0);
  #pragma unroll
  for (int r = 0; r < RW; r++)
    pb_cur[r] = pb[pbbase + (long)(q0 + w2 + r) * N + lane];
  if (t < QBL * 12) {
    int r = t / 12, c4 = t % 12;
    float4 val;
    if (c4 < 8)       val = *(const float4*)&q[(q0 + r) * C + hc32 + c4 * 4];
    else if (c4 < 11) val = *(const float4*)&qg[(q0 + r) * HP + h * 12 + (c4 - 8) * 4];
    else              val = make_float4(0.f, 0.f, 0.f, 0.f);
    val.x *= SCALING; val.y *= SCALING; val.z *= SCALING; val.w *= SCALING;
    *(float4*)&qc_s[r][c4 * 4] = val;
  }
  STAGE_WRITE(0);
  __syncthreads();

  float lsum0 = 0.f, lsum1 = 0.f;
  float o_[2][32] = {};

  for (int tile = 0; tile < NT; tile++) {
    int m0 = tile * MT;
    int cb = tile & 1;
    if (tile < NT - 1) {
      STAGE_LOAD(m0 + MT);
      #pragma unroll
      for (int r = 0; r < RW; r++)
        pb_nxt[r] = pb[pbbase + (long)(q0 + w2 + r) * N + m0 + MT + lane];
    }
    // ---- QK (lane=m): 11 swizzled b128 + 22 broadcasts ----
    float L0 = pb_cur[0], L1 = pb_cur[1];
    #pragma unroll
    for (int c4 = 0; c4 < 11; c4++) {
      float4 kv = *(const float4*)&kc_s[cb][lane * 64 + ((c4 ^ (lane & 7)) << 2)];
      float4 qv0 = *(const float4*)&qc_s[w2][c4 * 4];
      float4 qv1 = *(const float4*)&qc_s[w2 + 1][c4 * 4];
      L0 = fmaf(qv0.x, kv.x, L0); L0 = fmaf(qv0.y, kv.y, L0);
      L0 = fmaf(qv0.z, kv.z, L0); L0 = fmaf(qv0.w, kv.w, L0);
      L1 = fmaf(qv1.x, kv.x, L1); L1 = fmaf(qv1.y, kv.y, L1);
      L1 = fmaf(qv1.z, kv.z, L1); L1 = fmaf(qv1.w, kv.w, L1);
    }
    float p0 = __expf(L0), p1 = __expf(L1);   // max-free (validated r7/r8)
    lsum0 += p0; lsum1 += p1;
    // ---- AV (lane=m): 8 swizzled b128, p in registers, o_ private ----
    #pragma unroll
    for (int c4 = 0; c4 < 8; c4++) {
      float4 vv = *(const float4*)&v_s[cb][lane * 32 + ((c4 ^ (lane & 7)) << 2)];
      o_[0][c4*4+0] = fmaf(p0, vv.x, o_[0][c4*4+0]);
      o_[0][c4*4+1] = fmaf(p0, vv.y, o_[0][c4*4+1]);
      o_[0][c4*4+2] = fmaf(p0, vv.z, o_[0][c4*4+2]);
      o_[0][c4*4+3] = fmaf(p0, vv.w, o_[0][c4*4+3]);
      o_[1][c4*4+0] = fmaf(p1, vv.x, o_[1][c4*4+0]);
      o_[1][c4*4+1] = fmaf(p1, vv.y, o_[1][c4*4+1]);
      o_[1][c4*4+2] = fmaf(p1, vv.z, o_[1][c4*4+2]);
      o_[1][c4*4+3] = fmaf(p1, vv.w, o_[1][c4*4+3]);
    }
    if (tile < NT - 1) {
      STAGE_WRITE(cb ^ 1);           // other buffer: no WAR hazard
      #pragma unroll
      for (int r = 0; r < RW; r++) pb_cur[r] = pb_nxt[r];
    }
    __syncthreads();                 // one barrier per tile
  }

  #pragma unroll
  for (int off = 32; off; off >>= 1) {
    lsum0 += __shfl_xor(lsum0, off);
    lsum1 += __shfl_xor(lsum1, off);
  }
  // butterfly transpose-reduce (r10-proven): col c sum lands at lane c (c<32)
  #pragma unroll
  for (int r = 0; r < 2; r++) {
    float c16[16], c8[8], c4a[4], c2[2], c1;
    int b = lane & 1;
    #pragma unroll
    for (int j = 0; j < 16; j++) {
      float keep = b ? o_[r][2*j+1] : o_[r][2*j];
      float send = b ? o_[r][2*j]   : o_[r][2*j+1];
      c16[j] = keep + __shfl_xor(send, 1);
    }
    b = lane & 2;
    #pragma unroll
    for (int j = 0; j < 8; j++) {
      float keep = b ? c16[2*j+1] : c16[2*j];
      float send = b ? c16[2*j]   : c16[2*j+1];
      c8[j] = keep + __shfl_xor(send, 2);
    }
    b = lane & 4;
    #pragma unroll
    for (int j = 0; j < 4; j++) {
      float keep = b ? c8[2*j+1] : c8[2*j];
      float send = b ? c8[2*j]   : c8[2*j+1];
      c4a[j] = keep + __shfl_xor(send, 4);
    }
    b = lane & 8;
    #pragma unroll
    for (int j = 0; j < 2; j++) {
      float keep = b ? c4a[2*j+1] : c4a[2*j];
      float send = b ? c4a[2*j]   : c4a[2*j+1];
      c2[j] = keep + __shfl_xor(send, 8);
    }
    b = lane & 16;
    {
      float keep = b ? c2[1] : c2[0];
      float send = b ? c2[0] : c2[1];
      c1 = keep + __shfl_xor(send, 16);
    }
    c1 += __shfl_xor(c1, 32);
    float ls = (r == 0) ? lsum0 : lsum1;
    if (lane < 32) wt[(q0 + w2 + r) * C + hc32 + lane] = c1 / ls;
  }
#undef STAGE_LOAD
#undef STAGE_WRITE
#undef ST_KC
#undef ST_V
}

// ---------------- K4: output GEMM + residual + LayerNorm (r8, unchanged) ----------------
__global__ __launch_bounds__(384) void k_out(
    const float* __restrict__ wt, const float* __restrict__ Wo,
    const float* __restrict__ bo, const float* __restrict__ single,
    const float* __restrict__ gamma, const float* __restrict__ beta,
    float* __restrict__ out)
{
  __shared__ __align__(16) float wt_s[4 * C];
  __shared__ __align__(16) float red[4][2][6];
  int t = threadIdx.x, n0 = blockIdx.x * 4;
  for (int idx = t; idx < 4 * C; idx += 384) wt_s[idx] = wt[n0 * C + idx];
  __syncthreads();
  float acc[4] = {};
  for (int ck = 0; ck < C; ck++) {
    float w = Wo[ck * C + t];
    #pragma unroll
    for (int i = 0; i < 4; i++) acc[i] = fmaf(wt_s[i * C + ck], w, acc[i]);
  }
  float x[4], bov = bo[t];
  #pragma unroll
  for (int i = 0; i < 4; i++) x[i] = single[(n0 + i) * C + t] + acc[i] + bov;
  int wid = t >> 6, lane = t & 63;
  #pragma unroll
  for (int i = 0; i < 4; i++) {
    float s = x[i], s2 = x[i] * x[i];
    #pragma unroll
    for (int off = 32; off; off >>= 1) { s += __shfl_xor(s, off); s2 += __shfl_xor(s2, off); }
    if (lane == 0) { red[i][0][wid] = s; red[i][1][wid] = s2; }
  }
  __syncthreads();
  float gv = gamma[t], bv = beta[t];
  #pragma unroll
  for (int i = 0; i < 4; i++) {
    float S = 0.f, S2 = 0.f;
    #pragma unroll
    for (int w = 0; w < 6; w++) { S += red[i][0][w]; S2 += red[i][1][w]; }
    float mu = S * (1.0f / C);
    float var = S2 * (1.0f / C) - mu * mu;
    out[(n0 + i) * C + t] = (x[i] - mu) * rsqrtf(var + LN_EPS) * gv + bv;
  }
}

extern "C" void kernel_launch(void* const* d_in, const int* in_sizes, int n_in,
                              void* d_out, int out_size, void* d_ws, size_t ws_size,
                              hipStream_t stream) {
  const float* single = (const float*)d_in[0];
  const float* pair   = (const float*)d_in[1];
  const float* rot    = (const float*)d_in[2];
  const float* Wq  = (const float*)d_in[4];  const float* bq  = (const float*)d_in[5];
  const float* Wk  = (const float*)d_in[6];  const float* bk  = (const float*)d_in[7];
  const float* Wv  = (const float*)d_in[8];  const float* bv  = (const float*)d_in[9];
  const float* Wp  = (const float*)d_in[10]; const float* bp  = (const float*)d_in[11];
  const float* Wpq = (const float*)d_in[12]; const float* bpq = (const float*)d_in[13];
  const float* Wpk = (const float*)d_in[14]; const float* bpk = (const float*)d_in[15];
  const float* Wo  = (const float*)d_in[16]; const float* bo  = (const float*)d_in[17];
  const float* gamma = (const float*)d_in[18]; const float* beta = (const float*)d_in[19];

  float* ws   = (float*)d_ws;
  float* pb   = ws;                          // [12][N*N]
  float* q    = pb + 12L * N * N;            // [N][C]
  float* v    = q + N * C;                   // [N][C]
  float* qp   = v + N * C;                   // [N][HP]
  float* kp   = qp + N * HP;                 // [N][HP]
  float* qg   = kp + N * HP;                 // [N][HP]
  float* kcg  = qg + N * HP;                 // [12][N][48]
  float* sq   = kcg + 12L * N * 48;          // [N][12]
  float* sknh = sq + N * H;                  // [N][12]
  float* wt   = sknh + N * H;                // [N][C]

  k_qkv<<<dim3(30, 16), 256, 0, stream>>>(single, Wq, bq, Wk, bk, Wv, bv,
                                          Wpq, bpq, Wpk, bpk, q, kcg, v, qp, kp);
  k_rot<<<N, 256, 0, stream>>>(qp, kp, rot, qg, kcg, sq, sknh);
  k_pb<<<8192, 256, 0, stream>>>((const float4*)pair, Wp, bp, sq, sknh, pb);
  k_attn<<<1536, 256, 0, stream>>>(q, qg, kcg, v, pb, wt);
  k_out<<<256, 384, 0, stream>>>(wt, Wo, bo, single, gamma, beta, (float*)d_out);
}